// Round 3
// baseline (2622.530 us; speedup 1.0000x reference)
//
#include <hip/hip_runtime.h>
#include <hip/hip_bf16.h>
#include <cstdint>

constexpr int NB = 2, NS = 1024, ND = 1024, NH = 16, NL = 6, NV = 32000, NF = 4096, NDH = 64;

using bf16 = __hip_bfloat16;
typedef __bf16 bf16x8 __attribute__((ext_vector_type(8)));
typedef float f32x4 __attribute__((ext_vector_type(4)));

#define AS1(p) ((const __attribute__((address_space(1))) void*)(p))
#define AS3(p) ((__attribute__((address_space(3))) void*)(p))

__device__ __forceinline__ float gelu_f(float x) {
  // tanh-approx GELU via sigmoid: gelu(x) = x * sigmoid(2*0.79788456*(x+0.044715x^3))
  float z = 1.5957691216057308f * (x + 0.044715f * x * x * x);
  return x / (1.f + __expf(-z));
}

// ---------------- GEMM: C[M,N] = A[M,K] @ Bt[N,K]^T (+bias) ----------------
// EP: 0=f32 out, 1=bf16 out, 2=bf16 out w/ GELU, 3=f32 scatter-add rel-skew
// CZ: 0=none, 1=skip if n0>m0+BM-1 (causal QK), 2=kEnd=min(K,m0+BM) (causal PV),
//     3=skip tile fully left of rel-diagonal (QE)
template<int BN, int EP, int CZ, bool HASBIAS>
__global__ __launch_bounds__(256)
void gemm_bt(const bf16* __restrict__ A, const bf16* __restrict__ Bt,
             void* __restrict__ Cv, const float* __restrict__ bias,
             int M, int N, int K, int lda, int ldb, int ldc, int ZH,
             long sAb, long sAh, long sBb, long sBh, long sCb, long sCh, long sBias)
{
  constexpr int BM = 128, BK = 32;
  constexpr int WGN = (BN == 128) ? 2 : 1;
  constexpr int FM  = (BM / (4 / WGN)) / 16;
  constexpr int FN  = (BN / WGN) / 16;

  const int z  = blockIdx.z;
  const int zb = z / ZH, zh = z % ZH;
  const bf16* Ab = A + (long)zb * sAb + (long)zh * sAh;
  const bf16* Bb = Bt + (long)zb * sBb + (long)zh * sBh;

  const int m0 = blockIdx.y * BM;
  const int n0 = blockIdx.x * BN;

  if constexpr (CZ == 1) { if (n0 > m0 + BM - 1) return; }
  if constexpr (CZ == 3) { if (m0 + n0 + BM + BN - 2 < NS - 1) return; }

  int kEnd = K;
  if constexpr (CZ == 2) kEnd = (K < m0 + BM) ? K : (m0 + BM);

  __shared__ bf16 Asm[BM * BK];
  __shared__ bf16 Bsm[BN * BK];

  const int tid  = threadIdx.x;
  const int lane = tid & 63;
  const int wid  = tid >> 6;
  const int wm = (wid / WGN) * (FM * 16);
  const int wn = (wid % WGN) * (FN * 16);
  const int l15 = lane & 15;
  const int lk8 = (lane >> 4) * 8;

  f32x4 acc[FM][FN] = {};

  // staging: thread t covers row t/4, col (t%4)*8; linear LDS = t*16 bytes
  const int srow = tid >> 2;
  const int scol = (tid & 3) * 8;
  const bf16* gA = Ab + (long)(m0 + srow) * lda + scol;
  const bf16* gB = Bb + (long)(n0 + srow) * ldb + scol;
  bf16* ldsA = Asm + wid * 512;   // wave-uniform base; HW scatters lane*16B
  bf16* ldsB = Bsm + wid * 512;

  for (int k0 = 0; k0 < kEnd; k0 += BK) {
    __builtin_amdgcn_global_load_lds(AS1(gA + k0), AS3(ldsA), 16, 0, 0);
    __builtin_amdgcn_global_load_lds(AS1(gA + 64l * lda + k0), AS3(ldsA + 2048), 16, 0, 0);
    __builtin_amdgcn_global_load_lds(AS1(gB + k0), AS3(ldsB), 16, 0, 0);
    if constexpr (BN == 128)
      __builtin_amdgcn_global_load_lds(AS1(gB + 64l * ldb + k0), AS3(ldsB + 2048), 16, 0, 0);
    asm volatile("s_waitcnt vmcnt(0)" ::: "memory");
    __syncthreads();

    bf16x8 af[FM], bfr[FN];
    #pragma unroll
    for (int i = 0; i < FM; ++i)
      af[i] = *reinterpret_cast<const bf16x8*>(&Asm[(wm + i * 16 + l15) * BK + lk8]);
    #pragma unroll
    for (int j = 0; j < FN; ++j)
      bfr[j] = *reinterpret_cast<const bf16x8*>(&Bsm[(wn + j * 16 + l15) * BK + lk8]);
    #pragma unroll
    for (int i = 0; i < FM; ++i)
      #pragma unroll
      for (int j = 0; j < FN; ++j)
        acc[i][j] = __builtin_amdgcn_mfma_f32_16x16x32_bf16(af[i], bfr[j], acc[i][j], 0, 0, 0);
    __syncthreads();
  }

  const int rq = (lane >> 4) * 4;
  if constexpr (EP == 3) {
    // scatter-add: scores[q, q+m-(S-1)] += QE[q, m]
    float* C = (float*)Cv + (long)zb * sCb + (long)zh * sCh;
    #pragma unroll
    for (int i = 0; i < FM; ++i) {
      const int r0 = m0 + wm + i * 16 + rq;
      #pragma unroll
      for (int j = 0; j < FN; ++j) {
        const int cm = n0 + wn + j * 16 + l15;
        #pragma unroll
        for (int e = 0; e < 4; ++e) {
          const int tgt = (r0 + e) + cm - (NS - 1);
          if (tgt >= 0) C[(long)(r0 + e) * ldc + tgt] += acc[i][j][e];
        }
      }
    }
  } else {
    const long cb = (long)zb * sCb + (long)zh * sCh;
    #pragma unroll
    for (int i = 0; i < FM; ++i) {
      const int r0 = m0 + wm + i * 16 + rq;
      #pragma unroll
      for (int j = 0; j < FN; ++j) {
        const int c = n0 + wn + j * 16 + l15;
        float bv = 0.f;
        if constexpr (HASBIAS) bv = bias[(long)zb * sBias + c];
        #pragma unroll
        for (int e = 0; e < 4; ++e) {
          float v = acc[i][j][e] + bv;
          if constexpr (EP == 2) v = gelu_f(v);
          const long idx = cb + (long)(r0 + e) * ldc + c;
          if constexpr (EP == 0) ((float*)Cv)[idx] = v;
          else                   ((bf16*)Cv)[idx] = __float2bfloat16(v);
        }
      }
    }
  }
}

// ------------- transpose+convert: in f32 (R x C) -> out bf16 (C x R) -------------
__global__ void transpose_f32_bf16(const float* __restrict__ in, bf16* __restrict__ out,
                                   int R, int C, long inZ, long outZ) {
  __shared__ float t[32][33];
  const float* ip = in + (long)blockIdx.z * inZ;
  bf16* op = out + (long)blockIdx.z * outZ;
  const int c0 = blockIdx.x * 32, r0 = blockIdx.y * 32;
  const int tx = threadIdx.x, ty = threadIdx.y;
  #pragma unroll
  for (int i = 0; i < 4; ++i)
    t[ty * 4 + i][tx] = ip[(long)(r0 + ty * 4 + i) * C + c0 + tx];
  __syncthreads();
  #pragma unroll
  for (int i = 0; i < 4; ++i)
    op[(long)(c0 + ty * 4 + i) * R + r0 + tx] = __float2bfloat16(t[tx][ty * 4 + i]);
}

// v (B,S,D) -> vt (B,H,Dh,S)
__global__ void transpose_v_k(const bf16* __restrict__ v, bf16* __restrict__ vt) {
  __shared__ bf16 t[32][33];
  const int z = blockIdx.z, b = z >> 4, h = z & 15;
  const bf16* ip = v + (long)b * NS * ND + h * 64;
  bf16* op = vt + (long)z * 64 * NS;
  const int s0 = blockIdx.x * 32, d0 = blockIdx.y * 32;
  const int tx = threadIdx.x, ty = threadIdx.y;
  #pragma unroll
  for (int i = 0; i < 4; ++i)
    t[ty * 4 + i][tx] = ip[(long)(s0 + ty * 4 + i) * ND + d0 + tx];
  __syncthreads();
  #pragma unroll
  for (int i = 0; i < 4; ++i)
    op[(long)(d0 + ty * 4 + i) * NS + s0 + tx] = t[tx][ty * 4 + i];
}

__global__ void cvt_bf16_k(const float* __restrict__ in, bf16* __restrict__ out, int n) {
  int i = blockIdx.x * 256 + threadIdx.x;
  if (i < n) out[i] = __float2bfloat16(in[i]);
}

// pack bq,bk,bv (each L x D) -> out [L][3][D]
__global__ void pack3_k(const float* __restrict__ a, const float* __restrict__ b,
                        const float* __restrict__ c, float* __restrict__ out) {
  int i = blockIdx.x * 256 + threadIdx.x;
  if (i >= NL * 3 * ND) return;
  int d = i % ND, r = (i / ND) % 3, l = i / (3 * ND);
  const float* src = (r == 0) ? a : ((r == 1) ? b : c);
  out[i] = src[l * ND + d];
}

__global__ void embed_k(const int* __restrict__ tok, const float* __restrict__ emb,
                        float* __restrict__ x, bf16* __restrict__ xb) {
  const int row = blockIdx.x;
  const int t = tok[row];
  const float4 val = ((const float4*)(emb + (long)t * ND))[threadIdx.x];
  ((float4*)(x + (long)row * ND))[threadIdx.x] = val;
  bf16* xp = xb + (long)row * ND + threadIdx.x * 4;
  xp[0] = __float2bfloat16(val.x); xp[1] = __float2bfloat16(val.y);
  xp[2] = __float2bfloat16(val.z); xp[3] = __float2bfloat16(val.w);
}

// causal softmax, one wave per row; writes bf16 P in place over the f32 row
__global__ void softmax_k(float* __restrict__ sc) {
  const int row = blockIdx.x * 4 + (threadIdx.x >> 6);
  const int lane = threadIdx.x & 63;
  const int q = row & (NS - 1);
  float* p = sc + (long)row * NS;
  float v[16];
  float mx = -1e30f;
  #pragma unroll
  for (int i = 0; i < 16; ++i) {
    const int idx = i * 64 + lane;
    const float t = p[idx];
    v[i] = (idx <= q) ? t * 0.125f : -1e30f;   // *1/sqrt(64); mask
    mx = fmaxf(mx, v[i]);
  }
  #pragma unroll
  for (int o = 32; o; o >>= 1) mx = fmaxf(mx, __shfl_xor(mx, o));
  float sum = 0.f;
  #pragma unroll
  for (int i = 0; i < 16; ++i) {
    const int idx = i * 64 + lane;
    const float e = (idx <= q) ? __expf(v[i] - mx) : 0.f;
    v[i] = e; sum += e;
  }
  #pragma unroll
  for (int o = 32; o; o >>= 1) sum += __shfl_xor(sum, o);
  const float r = 1.f / sum;
  bf16* ob = (bf16*)p;
  #pragma unroll
  for (int i = 0; i < 16; ++i) ob[i * 64 + lane] = __float2bfloat16(v[i] * r);
}

// x = LN(x + g) * s + b (in place on x), also emit xb = bf16(x)
__global__ void resid_ln_k(float* __restrict__ x, const float* __restrict__ g,
                           const float* __restrict__ s, const float* __restrict__ b,
                           bf16* __restrict__ xb) {
  const int row = blockIdx.x, tid = threadIdx.x;
  const float4 xv = ((const float4*)(x + (long)row * ND))[tid];
  const float4 gv = ((const float4*)(g + (long)row * ND))[tid];
  float h0 = xv.x + gv.x, h1 = xv.y + gv.y, h2 = xv.z + gv.z, h3 = xv.w + gv.w;
  float ls = h0 + h1 + h2 + h3;
  __shared__ float red[8];
  #pragma unroll
  for (int o = 32; o; o >>= 1) ls += __shfl_xor(ls, o);
  const int lane = tid & 63, wid = tid >> 6;
  if (lane == 0) red[wid] = ls;
  __syncthreads();
  const float mu = (red[0] + red[1] + red[2] + red[3]) * (1.f / ND);
  const float d0 = h0 - mu, d1 = h1 - mu, d2 = h2 - mu, d3 = h3 - mu;
  float lv = d0 * d0 + d1 * d1 + d2 * d2 + d3 * d3;
  #pragma unroll
  for (int o = 32; o; o >>= 1) lv += __shfl_xor(lv, o);
  if (lane == 0) red[4 + wid] = lv;
  __syncthreads();
  const float rs = rsqrtf((red[4] + red[5] + red[6] + red[7]) * (1.f / ND) + 1e-5f);
  const float4 sv = ((const float4*)s)[tid];
  const float4 bv = ((const float4*)b)[tid];
  const float y0 = d0 * rs * sv.x + bv.x, y1 = d1 * rs * sv.y + bv.y;
  const float y2 = d2 * rs * sv.z + bv.z, y3 = d3 * rs * sv.w + bv.w;
  ((float4*)(x + (long)row * ND))[tid] = make_float4(y0, y1, y2, y3);
  bf16* xp = xb + (long)row * ND + tid * 4;
  xp[0] = __float2bfloat16(y0); xp[1] = __float2bfloat16(y1);
  xp[2] = __float2bfloat16(y2); xp[3] = __float2bfloat16(y3);
}

extern "C" void kernel_launch(void* const* d_in, const int* in_sizes, int n_in,
                              void* d_out, int out_size, void* d_ws, size_t ws_size,
                              hipStream_t stream) {
  const int*   tokens = (const int*)d_in[0];
  const float* emb  = (const float*)d_in[1];
  const float* Wq   = (const float*)d_in[2];
  const float* bq   = (const float*)d_in[3];
  const float* Wk   = (const float*)d_in[4];
  const float* bk   = (const float*)d_in[5];
  const float* Wv   = (const float*)d_in[6];
  const float* bv   = (const float*)d_in[7];
  const float* Wo   = (const float*)d_in[8];
  const float* bo   = (const float*)d_in[9];
  const float* rpe  = (const float*)d_in[10];
  const float* ln1s = (const float*)d_in[11];
  const float* ln1b = (const float*)d_in[12];
  const float* ln2s = (const float*)d_in[13];
  const float* ln2b = (const float*)d_in[14];
  const float* W1   = (const float*)d_in[15];
  const float* b1   = (const float*)d_in[16];
  const float* W2   = (const float*)d_in[17];
  const float* b2   = (const float*)d_in[18];
  const float* Wout = (const float*)d_in[19];
  const float* bout = (const float*)d_in[20];
  float* out = (float*)d_out;

  char* wsb = (char*)d_ws;
  size_t off = 0;
  auto take = [&](size_t bytes) -> void* {
    void* r = wsb + off;
    off = (off + bytes + 255) & ~(size_t)255;
    return r;
  };
  bf16*  wqkvT = (bf16*)take((size_t)NL * 3 * ND * ND * 2);   // [L][3][N=D][K=D]
  bf16*  woT   = (bf16*)take((size_t)NL * ND * ND * 2);
  bf16*  w1T   = (bf16*)take((size_t)NL * NF * ND * 2);       // [L][N=F][K=D]
  bf16*  w2T   = (bf16*)take((size_t)NL * ND * NF * 2);       // [L][N=D][K=F]
  bf16*  woutT = (bf16*)take((size_t)NV * ND * 2);            // [N=V][K=D]
  bf16*  rpeb  = (bf16*)take((size_t)NL * NS * NDH * 2);
  float* qkvb  = (float*)take((size_t)NL * 3 * ND * 4);
  float* x     = (float*)take((size_t)NB * NS * ND * 4);
  bf16*  xb    = (bf16*)take((size_t)NB * NS * ND * 2);
  bf16*  qkv   = (bf16*)take((size_t)3 * NB * NS * ND * 2);   // [3][B][S][D]
  bf16*  vt    = (bf16*)take((size_t)NB * NS * ND * 2);       // [B][H][Dh][S]
  bf16*  ob    = (bf16*)take((size_t)NB * NS * ND * 2);
  float* g     = (float*)take((size_t)NB * NS * NF * 4);
  bf16*  hbuf  = (bf16*)take((size_t)NB * NS * NF * 2);
  float* sc    = (float*)take((size_t)NB * NH * NS * NS * 4);
  (void)in_sizes; (void)n_in; (void)out_size; (void)ws_size;

  const dim3 tb(32, 8);
  // weight transposes (f32 -> bf16, B^T layout)
  transpose_f32_bf16<<<dim3(ND/32, ND/32, NL), tb, 0, stream>>>(Wq, wqkvT,                      ND, ND, (long)ND*ND, (long)3*ND*ND);
  transpose_f32_bf16<<<dim3(ND/32, ND/32, NL), tb, 0, stream>>>(Wk, wqkvT + (size_t)ND*ND,      ND, ND, (long)ND*ND, (long)3*ND*ND);
  transpose_f32_bf16<<<dim3(ND/32, ND/32, NL), tb, 0, stream>>>(Wv, wqkvT + (size_t)2*ND*ND,    ND, ND, (long)ND*ND, (long)3*ND*ND);
  transpose_f32_bf16<<<dim3(ND/32, ND/32, NL), tb, 0, stream>>>(Wo, woT,                        ND, ND, (long)ND*ND, (long)ND*ND);
  transpose_f32_bf16<<<dim3(NF/32, ND/32, NL), tb, 0, stream>>>(W1, w1T,                        ND, NF, (long)ND*NF, (long)NF*ND);
  transpose_f32_bf16<<<dim3(ND/32, NF/32, NL), tb, 0, stream>>>(W2, w2T,                        NF, ND, (long)NF*ND, (long)ND*NF);
  transpose_f32_bf16<<<dim3(NV/32, ND/32, 1),  tb, 0, stream>>>(Wout, woutT,                    ND, NV, 0, 0);
  cvt_bf16_k<<<(NL*NS*NDH + 255)/256, 256, 0, stream>>>(rpe, rpeb, NL*NS*NDH);
  pack3_k<<<(NL*3*ND + 255)/256, 256, 0, stream>>>(bq, bk, bv, qkvb);
  embed_k<<<NB*NS, 256, 0, stream>>>(tokens, emb, x, xb);

  for (int l = 0; l < NL; ++l) {
    // QKV projections (batched z=0,1,2), bf16 out + bias
    gemm_bt<128, 1, 0, true><<<dim3(ND/128, NB*NS/128, 3), 256, 0, stream>>>(
        xb, wqkvT + (size_t)l*3*ND*ND, qkv, qkvb + (size_t)l*3*ND,
        NB*NS, ND, ND, ND, ND, ND, 1,
        0, 0, (long)ND*ND, 0, (long)NB*NS*ND, 0, ND);
    transpose_v_k<<<dim3(NS/32, 2, NB*NH), tb, 0, stream>>>(qkv + (size_t)2*NB*NS*ND, vt);
    // QK^T -> scores (f32), causal tile skip
    gemm_bt<128, 0, 1, false><<<dim3(NS/128, NS/128, NB*NH), 256, 0, stream>>>(
        qkv, qkv + (size_t)NB*NS*ND, sc, nullptr,
        NS, NS, NDH, ND, ND, NS, NH,
        (long)NS*ND, 64, (long)NS*ND, 64, (long)NH*NS*NS, (long)NS*NS, 0);
    // Q @ E^T, skew-scatter-add into scores
    gemm_bt<128, 3, 3, false><<<dim3(NS/128, NS/128, NB*NH), 256, 0, stream>>>(
        qkv, rpeb + (size_t)l*NS*NDH, sc, nullptr,
        NS, NS, NDH, ND, NDH, NS, NH,
        (long)NS*ND, 64, 0, 0, (long)NH*NS*NS, (long)NS*NS, 0);
    softmax_k<<<NB*NH*NS/4, 256, 0, stream>>>(sc);
    // P @ V -> attn out (bf16, scattered into (B,S,D) by head), causal kEnd
    gemm_bt<64, 1, 2, false><<<dim3(1, NS/128, NB*NH), 256, 0, stream>>>(
        (const bf16*)sc, vt, ob, nullptr,
        NS, NDH, NS, 2*NS, NS, ND, NH,
        (long)NH*NS*NS*2, (long)NS*NS*2, (long)NH*NDH*NS, (long)NDH*NS, (long)NS*ND, 64, 0);
    // O projection -> g (f32) + bias
    gemm_bt<128, 0, 0, true><<<dim3(ND/128, NB*NS/128, 1), 256, 0, stream>>>(
        ob, woT + (size_t)l*ND*ND, g, bo + (size_t)l*ND,
        NB*NS, ND, ND, ND, ND, ND, 1, 0,0, 0,0, 0,0, 0);
    resid_ln_k<<<NB*NS, 256, 0, stream>>>(x, g, ln1s + (size_t)l*ND, ln1b + (size_t)l*ND, xb);
    // FFN1: bias + GELU fused, bf16 out
    gemm_bt<128, 2, 0, true><<<dim3(NF/128, NB*NS/128, 1), 256, 0, stream>>>(
        xb, w1T + (size_t)l*NF*ND, hbuf, b1 + (size_t)l*NF,
        NB*NS, NF, ND, ND, ND, NF, 1, 0,0, 0,0, 0,0, 0);
    // FFN2 -> g (f32) + bias
    gemm_bt<128, 0, 0, true><<<dim3(ND/128, NB*NS/128, 1), 256, 0, stream>>>(
        hbuf, w2T + (size_t)l*ND*NF, g, b2 + (size_t)l*ND,
        NB*NS, ND, NF, NF, NF, ND, 1, 0,0, 0,0, 0,0, 0);
    resid_ln_k<<<NB*NS, 256, 0, stream>>>(x, g, ln2s + (size_t)l*ND, ln2b + (size_t)l*ND, xb);
  }
  // final vocab projection (f32 out + bias)
  gemm_bt<128, 0, 0, true><<<dim3(NV/128, NB*NS/128, 1), 256, 0, stream>>>(
      xb, woutT, out, bout,
      NB*NS, NV, ND, ND, ND, NV, 1, 0,0, 0,0, 0,0, 0);
}

// Round 4
// 2616.726 us; speedup vs baseline: 1.0022x; 1.0022x over previous
//
#include <hip/hip_runtime.h>
#include <hip/hip_bf16.h>
#include <cstdint>

constexpr int NB = 2, NS = 1024, ND = 1024, NH = 16, NL = 6, NV = 32000, NF = 4096, NDH = 64;

using bf16 = __hip_bfloat16;
typedef __bf16 bf16x8 __attribute__((ext_vector_type(8)));
typedef float f32x4 __attribute__((ext_vector_type(4)));

#define AS1(p) ((const __attribute__((address_space(1))) void*)(p))
#define AS3(p) ((__attribute__((address_space(3))) void*)(p))

__device__ __forceinline__ float gelu_f(float x) {
  // tanh-approx GELU via sigmoid: gelu(x) = x * sigmoid(2*0.79788456*(x+0.044715x^3))
  float z = 1.5957691216057308f * (x + 0.044715f * x * x * x);
  return x / (1.f + __expf(-z));
}

// ---------------- GEMM: C[M,N] = A[M,K] @ Bt[N,K]^T (+bias) ----------------
// EP: 0=f32 out, 1=bf16 out, 2=bf16 out w/ GELU, 3=f32 scatter-add rel-skew
// CZ: 0=none, 1=skip if n0>m0+BM-1 (causal QK), 2=kEnd=min(K,m0+BM) (causal PV),
//     3=skip tile fully left of rel-diagonal (QE)
template<int BN, int EP, int CZ, bool HASBIAS>
__global__ __launch_bounds__(256)
void gemm_bt(const bf16* __restrict__ A, const bf16* __restrict__ Bt,
             void* __restrict__ Cv, const float* __restrict__ bias,
             int M, int N, int K, int lda, int ldb, int ldc, int ZH,
             long sAb, long sAh, long sBb, long sBh, long sCb, long sCh, long sBias)
{
  constexpr int BM = 128, BK = 32;
  constexpr int WGN = (BN == 128) ? 2 : 1;
  constexpr int FM  = (BM / (4 / WGN)) / 16;
  constexpr int FN  = (BN / WGN) / 16;

  const int z  = blockIdx.z;
  const int zb = z / ZH, zh = z % ZH;
  const bf16* Ab = A + (long)zb * sAb + (long)zh * sAh;
  const bf16* Bb = Bt + (long)zb * sBb + (long)zh * sBh;

  const int m0 = blockIdx.y * BM;
  const int n0 = blockIdx.x * BN;

  if constexpr (CZ == 1) { if (n0 > m0 + BM - 1) return; }
  if constexpr (CZ == 3) { if (m0 + n0 + BM + BN - 2 < NS - 1) return; }

  int kEnd = K;
  if constexpr (CZ == 2) kEnd = (K < m0 + BM) ? K : (m0 + BM);

  __shared__ bf16 Asm[BM * BK];
  __shared__ bf16 Bsm[BN * BK];

  const int tid  = threadIdx.x;
  const int lane = tid & 63;
  const int wid  = tid >> 6;
  const int wm = (wid / WGN) * (FM * 16);
  const int wn = (wid % WGN) * (FN * 16);
  const int l15 = lane & 15;
  const int lk8 = (lane >> 4) * 8;

  f32x4 acc[FM][FN] = {};

  // staging: thread t covers row t/4, col (t%4)*8; linear LDS = t*16 bytes
  const int srow = tid >> 2;
  const int scol = (tid & 3) * 8;
  const bf16* gA = Ab + (long)(m0 + srow) * lda + scol;
  const bf16* gB = Bb + (long)(n0 + srow) * ldb + scol;
  bf16* ldsA = Asm + wid * 512;   // wave-uniform base; HW scatters lane*16B
  bf16* ldsB = Bsm + wid * 512;

  for (int k0 = 0; k0 < kEnd; k0 += BK) {
    __builtin_amdgcn_global_load_lds(AS1(gA + k0), AS3(ldsA), 16, 0, 0);
    __builtin_amdgcn_global_load_lds(AS1(gA + 64l * lda + k0), AS3(ldsA + 2048), 16, 0, 0);
    __builtin_amdgcn_global_load_lds(AS1(gB + k0), AS3(ldsB), 16, 0, 0);
    if constexpr (BN == 128)
      __builtin_amdgcn_global_load_lds(AS1(gB + 64l * ldb + k0), AS3(ldsB + 2048), 16, 0, 0);
    asm volatile("s_waitcnt vmcnt(0)" ::: "memory");
    __syncthreads();

    bf16x8 af[FM], bfr[FN];
    #pragma unroll
    for (int i = 0; i < FM; ++i)
      af[i] = *reinterpret_cast<const bf16x8*>(&Asm[(wm + i * 16 + l15) * BK + lk8]);
    #pragma unroll
    for (int j = 0; j < FN; ++j)
      bfr[j] = *reinterpret_cast<const bf16x8*>(&Bsm[(wn + j * 16 + l15) * BK + lk8]);
    #pragma unroll
    for (int i = 0; i < FM; ++i)
      #pragma unroll
      for (int j = 0; j < FN; ++j)
        acc[i][j] = __builtin_amdgcn_mfma_f32_16x16x32_bf16(af[i], bfr[j], acc[i][j], 0, 0, 0);
    __syncthreads();
  }

  const int rq = (lane >> 4) * 4;
  if constexpr (EP == 3) {
    // scatter-add: scores[q, q+m-(S-1)] += QE[q, m]
    float* C = (float*)Cv + (long)zb * sCb + (long)zh * sCh;
    #pragma unroll
    for (int i = 0; i < FM; ++i) {
      const int r0 = m0 + wm + i * 16 + rq;
      #pragma unroll
      for (int j = 0; j < FN; ++j) {
        const int cm = n0 + wn + j * 16 + l15;
        #pragma unroll
        for (int e = 0; e < 4; ++e) {
          const int tgt = (r0 + e) + cm - (NS - 1);
          if (tgt >= 0) C[(long)(r0 + e) * ldc + tgt] += acc[i][j][e];
        }
      }
    }
  } else {
    const long cb = (long)zb * sCb + (long)zh * sCh;
    #pragma unroll
    for (int i = 0; i < FM; ++i) {
      const int r0 = m0 + wm + i * 16 + rq;
      #pragma unroll
      for (int j = 0; j < FN; ++j) {
        const int c = n0 + wn + j * 16 + l15;
        float bv = 0.f;
        if constexpr (HASBIAS) bv = bias[(long)zb * sBias + c];
        #pragma unroll
        for (int e = 0; e < 4; ++e) {
          float v = acc[i][j][e] + bv;
          if constexpr (EP == 2) v = gelu_f(v);
          const long idx = cb + (long)(r0 + e) * ldc + c;
          if constexpr (EP == 0) ((float*)Cv)[idx] = v;
          else                   ((bf16*)Cv)[idx] = __float2bfloat16(v);
        }
      }
    }
  }
}

// ------------- transpose+convert: in f32 (R x C) -> out bf16 (C x R) -------------
__global__ void transpose_f32_bf16(const float* __restrict__ in, bf16* __restrict__ out,
                                   int R, int C, long inZ, long outZ) {
  __shared__ float t[32][33];
  const float* ip = in + (long)blockIdx.z * inZ;
  bf16* op = out + (long)blockIdx.z * outZ;
  const int c0 = blockIdx.x * 32, r0 = blockIdx.y * 32;
  const int tx = threadIdx.x, ty = threadIdx.y;
  #pragma unroll
  for (int i = 0; i < 4; ++i)
    t[ty * 4 + i][tx] = ip[(long)(r0 + ty * 4 + i) * C + c0 + tx];
  __syncthreads();
  #pragma unroll
  for (int i = 0; i < 4; ++i)
    op[(long)(c0 + ty * 4 + i) * R + r0 + tx] = __float2bfloat16(t[tx][ty * 4 + i]);
}

// v (B,S,D) -> vt (B,H,Dh,S)
__global__ void transpose_v_k(const bf16* __restrict__ v, bf16* __restrict__ vt) {
  __shared__ bf16 t[32][33];
  const int z = blockIdx.z, b = z >> 4, h = z & 15;
  const bf16* ip = v + (long)b * NS * ND + h * 64;
  bf16* op = vt + (long)z * 64 * NS;
  const int s0 = blockIdx.x * 32, d0 = blockIdx.y * 32;
  const int tx = threadIdx.x, ty = threadIdx.y;
  #pragma unroll
  for (int i = 0; i < 4; ++i)
    t[ty * 4 + i][tx] = ip[(long)(s0 + ty * 4 + i) * ND + d0 + tx];
  __syncthreads();
  #pragma unroll
  for (int i = 0; i < 4; ++i)
    op[(long)(d0 + ty * 4 + i) * NS + s0 + tx] = t[tx][ty * 4 + i];
}

__global__ void cvt_bf16_k(const float* __restrict__ in, bf16* __restrict__ out, int n) {
  int i = blockIdx.x * 256 + threadIdx.x;
  if (i < n) out[i] = __float2bfloat16(in[i]);
}

// pack bq,bk,bv (each L x D) -> out [L][3][D]
__global__ void pack3_k(const float* __restrict__ a, const float* __restrict__ b,
                        const float* __restrict__ c, float* __restrict__ out) {
  int i = blockIdx.x * 256 + threadIdx.x;
  if (i >= NL * 3 * ND) return;
  int d = i % ND, r = (i / ND) % 3, l = i / (3 * ND);
  const float* src = (r == 0) ? a : ((r == 1) ? b : c);
  out[i] = src[l * ND + d];
}

__global__ void embed_k(const int* __restrict__ tok, const float* __restrict__ emb,
                        float* __restrict__ x, bf16* __restrict__ xb) {
  const int row = blockIdx.x;
  const int t = tok[row];
  const float4 val = ((const float4*)(emb + (long)t * ND))[threadIdx.x];
  ((float4*)(x + (long)row * ND))[threadIdx.x] = val;
  bf16* xp = xb + (long)row * ND + threadIdx.x * 4;
  xp[0] = __float2bfloat16(val.x); xp[1] = __float2bfloat16(val.y);
  xp[2] = __float2bfloat16(val.z); xp[3] = __float2bfloat16(val.w);
}

// causal softmax, one wave per row; writes bf16 P in place over the f32 row
__global__ void softmax_k(float* __restrict__ sc) {
  const int row = blockIdx.x * 4 + (threadIdx.x >> 6);
  const int lane = threadIdx.x & 63;
  const int q = row & (NS - 1);
  float* p = sc + (long)row * NS;
  float v[16];
  float mx = -1e30f;
  #pragma unroll
  for (int i = 0; i < 16; ++i) {
    const int idx = i * 64 + lane;
    const float t = p[idx];
    v[i] = (idx <= q) ? t * 0.125f : -1e30f;   // *1/sqrt(64); mask
    mx = fmaxf(mx, v[i]);
  }
  #pragma unroll
  for (int o = 32; o; o >>= 1) mx = fmaxf(mx, __shfl_xor(mx, o));
  float sum = 0.f;
  #pragma unroll
  for (int i = 0; i < 16; ++i) {
    const int idx = i * 64 + lane;
    const float e = (idx <= q) ? __expf(v[i] - mx) : 0.f;
    v[i] = e; sum += e;
  }
  #pragma unroll
  for (int o = 32; o; o >>= 1) sum += __shfl_xor(sum, o);
  const float r = 1.f / sum;
  bf16* ob = (bf16*)p;
  #pragma unroll
  for (int i = 0; i < 16; ++i) ob[i * 64 + lane] = __float2bfloat16(v[i] * r);
}

// x = LN(x + g) * s + b (in place on x), also emit xb = bf16(x)
__global__ void resid_ln_k(float* __restrict__ x, const float* __restrict__ g,
                           const float* __restrict__ s, const float* __restrict__ b,
                           bf16* __restrict__ xb) {
  const int row = blockIdx.x, tid = threadIdx.x;
  const float4 xv = ((const float4*)(x + (long)row * ND))[tid];
  const float4 gv = ((const float4*)(g + (long)row * ND))[tid];
  float h0 = xv.x + gv.x, h1 = xv.y + gv.y, h2 = xv.z + gv.z, h3 = xv.w + gv.w;
  float ls = h0 + h1 + h2 + h3;
  __shared__ float red[8];
  #pragma unroll
  for (int o = 32; o; o >>= 1) ls += __shfl_xor(ls, o);
  const int lane = tid & 63, wid = tid >> 6;
  if (lane == 0) red[wid] = ls;
  __syncthreads();
  const float mu = (red[0] + red[1] + red[2] + red[3]) * (1.f / ND);
  const float d0 = h0 - mu, d1 = h1 - mu, d2 = h2 - mu, d3 = h3 - mu;
  float lv = d0 * d0 + d1 * d1 + d2 * d2 + d3 * d3;
  #pragma unroll
  for (int o = 32; o; o >>= 1) lv += __shfl_xor(lv, o);
  if (lane == 0) red[4 + wid] = lv;
  __syncthreads();
  const float rs = rsqrtf((red[4] + red[5] + red[6] + red[7]) * (1.f / ND) + 1e-5f);
  const float4 sv = ((const float4*)s)[tid];
  const float4 bv = ((const float4*)b)[tid];
  const float y0 = d0 * rs * sv.x + bv.x, y1 = d1 * rs * sv.y + bv.y;
  const float y2 = d2 * rs * sv.z + bv.z, y3 = d3 * rs * sv.w + bv.w;
  ((float4*)(x + (long)row * ND))[tid] = make_float4(y0, y1, y2, y3);
  bf16* xp = xb + (long)row * ND + tid * 4;
  xp[0] = __float2bfloat16(y0); xp[1] = __float2bfloat16(y1);
  xp[2] = __float2bfloat16(y2); xp[3] = __float2bfloat16(y3);
}

extern "C" void kernel_launch(void* const* d_in, const int* in_sizes, int n_in,
                              void* d_out, int out_size, void* d_ws, size_t ws_size,
                              hipStream_t stream) {
  const int*   tokens = (const int*)d_in[0];
  const float* emb  = (const float*)d_in[1];
  const float* Wq   = (const float*)d_in[2];
  const float* bq   = (const float*)d_in[3];
  const float* Wk   = (const float*)d_in[4];
  const float* bk   = (const float*)d_in[5];
  const float* Wv   = (const float*)d_in[6];
  const float* bv   = (const float*)d_in[7];
  const float* Wo   = (const float*)d_in[8];
  const float* bo   = (const float*)d_in[9];
  const float* rpe  = (const float*)d_in[10];
  const float* ln1s = (const float*)d_in[11];
  const float* ln1b = (const float*)d_in[12];
  const float* ln2s = (const float*)d_in[13];
  const float* ln2b = (const float*)d_in[14];
  const float* W1   = (const float*)d_in[15];
  const float* b1   = (const float*)d_in[16];
  const float* W2   = (const float*)d_in[17];
  const float* b2   = (const float*)d_in[18];
  const float* Wout = (const float*)d_in[19];
  const float* bout = (const float*)d_in[20];
  float* out = (float*)d_out;

  char* wsb = (char*)d_ws;
  size_t off = 0;
  auto take = [&](size_t bytes) -> void* {
    void* r = wsb + off;
    off = (off + bytes + 255) & ~(size_t)255;
    return r;
  };
  bf16*  wqkvT = (bf16*)take((size_t)NL * 3 * ND * ND * 2);   // [L][3][N=D][K=D]
  bf16*  woT   = (bf16*)take((size_t)NL * ND * ND * 2);
  bf16*  w1T   = (bf16*)take((size_t)NL * NF * ND * 2);       // [L][N=F][K=D]
  bf16*  w2T   = (bf16*)take((size_t)NL * ND * NF * 2);       // [L][N=D][K=F]
  bf16*  woutT = (bf16*)take((size_t)NV * ND * 2);            // [N=V][K=D]
  bf16*  rpeb  = (bf16*)take((size_t)NL * NS * NDH * 2);
  float* qkvb  = (float*)take((size_t)NL * 3 * ND * 4);
  float* x     = (float*)take((size_t)NB * NS * ND * 4);
  bf16*  xb    = (bf16*)take((size_t)NB * NS * ND * 2);
  bf16*  qkv   = (bf16*)take((size_t)3 * NB * NS * ND * 2);   // [3][B][S][D]
  bf16*  vt    = (bf16*)take((size_t)NB * NS * ND * 2);       // [B][H][Dh][S]
  bf16*  ob    = (bf16*)take((size_t)NB * NS * ND * 2);
  float* g     = (float*)take((size_t)NB * NS * NF * 4);
  bf16*  hbuf  = (bf16*)take((size_t)NB * NS * NF * 2);
  float* sc    = (float*)take((size_t)NB * NH * NS * NS * 4);
  (void)in_sizes; (void)n_in; (void)out_size; (void)ws_size;

  const dim3 tb(32, 8);
  // weight transposes (f32 -> bf16, B^T layout)
  transpose_f32_bf16<<<dim3(ND/32, ND/32, NL), tb, 0, stream>>>(Wq, wqkvT,                      ND, ND, (long)ND*ND, (long)3*ND*ND);
  transpose_f32_bf16<<<dim3(ND/32, ND/32, NL), tb, 0, stream>>>(Wk, wqkvT + (size_t)ND*ND,      ND, ND, (long)ND*ND, (long)3*ND*ND);
  transpose_f32_bf16<<<dim3(ND/32, ND/32, NL), tb, 0, stream>>>(Wv, wqkvT + (size_t)2*ND*ND,    ND, ND, (long)ND*ND, (long)3*ND*ND);
  transpose_f32_bf16<<<dim3(ND/32, ND/32, NL), tb, 0, stream>>>(Wo, woT,                        ND, ND, (long)ND*ND, (long)ND*ND);
  transpose_f32_bf16<<<dim3(NF/32, ND/32, NL), tb, 0, stream>>>(W1, w1T,                        ND, NF, (long)ND*NF, (long)NF*ND);
  transpose_f32_bf16<<<dim3(ND/32, NF/32, NL), tb, 0, stream>>>(W2, w2T,                        NF, ND, (long)NF*ND, (long)ND*NF);
  transpose_f32_bf16<<<dim3(NV/32, ND/32, 1),  tb, 0, stream>>>(Wout, woutT,                    ND, NV, 0, 0);
  cvt_bf16_k<<<(NL*NS*NDH + 255)/256, 256, 0, stream>>>(rpe, rpeb, NL*NS*NDH);
  pack3_k<<<(NL*3*ND + 255)/256, 256, 0, stream>>>(bq, bk, bv, qkvb);
  embed_k<<<NB*NS, 256, 0, stream>>>(tokens, emb, x, xb);

  for (int l = 0; l < NL; ++l) {
    // QKV projections (batched z=0,1,2), bf16 out + bias
    gemm_bt<128, 1, 0, true><<<dim3(ND/128, NB*NS/128, 3), 256, 0, stream>>>(
        xb, wqkvT + (size_t)l*3*ND*ND, qkv, qkvb + (size_t)l*3*ND,
        NB*NS, ND, ND, ND, ND, ND, 1,
        0, 0, (long)ND*ND, 0, (long)NB*NS*ND, 0, ND);
    transpose_v_k<<<dim3(NS/32, 2, NB*NH), tb, 0, stream>>>(qkv + (size_t)2*NB*NS*ND, vt);
    // QK^T -> scores (f32), causal tile skip
    gemm_bt<128, 0, 1, false><<<dim3(NS/128, NS/128, NB*NH), 256, 0, stream>>>(
        qkv, qkv + (size_t)NB*NS*ND, sc, nullptr,
        NS, NS, NDH, ND, ND, NS, NH,
        (long)NS*ND, 64, (long)NS*ND, 64, (long)NH*NS*NS, (long)NS*NS, 0);
    // Q @ E^T, skew-scatter-add into scores
    gemm_bt<128, 3, 3, false><<<dim3(NS/128, NS/128, NB*NH), 256, 0, stream>>>(
        qkv, rpeb + (size_t)l*NS*NDH, sc, nullptr,
        NS, NS, NDH, ND, NDH, NS, NH,
        (long)NS*ND, 64, 0, 0, (long)NH*NS*NS, (long)NS*NS, 0);
    softmax_k<<<NB*NH*NS/4, 256, 0, stream>>>(sc);
    // P @ V -> attn out (bf16, scattered into (B,S,D) by head), causal kEnd
    gemm_bt<64, 1, 2, false><<<dim3(1, NS/128, NB*NH), 256, 0, stream>>>(
        (const bf16*)sc, vt, ob, nullptr,
        NS, NDH, NS, 2*NS, NS, ND, NH,
        (long)NH*NS*NS*2, (long)NS*NS*2, (long)NH*NDH*NS, (long)NDH*NS, (long)NS*ND, 64, 0);
    // O projection -> g (f32) + bias
    gemm_bt<128, 0, 0, true><<<dim3(ND/128, NB*NS/128, 1), 256, 0, stream>>>(
        ob, woT + (size_t)l*ND*ND, g, bo + (size_t)l*ND,
        NB*NS, ND, ND, ND, ND, ND, 1, 0,0, 0,0, 0,0, 0);
    resid_ln_k<<<NB*NS, 256, 0, stream>>>(x, g, ln1s + (size_t)l*ND, ln1b + (size_t)l*ND, xb);
    // FFN1: bias + GELU fused, bf16 out
    gemm_bt<128, 2, 0, true><<<dim3(NF/128, NB*NS/128, 1), 256, 0, stream>>>(
        xb, w1T + (size_t)l*NF*ND, hbuf, b1 + (size_t)l*NF,
        NB*NS, NF, ND, ND, ND, NF, 1, 0,0, 0,0, 0,0, 0);
    // FFN2 -> g (f32) + bias
    gemm_bt<128, 0, 0, true><<<dim3(ND/128, NB*NS/128, 1), 256, 0, stream>>>(
        hbuf, w2T + (size_t)l*ND*NF, g, b2 + (size_t)l*ND,
        NB*NS, ND, NF, NF, NF, ND, 1, 0,0, 0,0, 0,0, 0);
    resid_ln_k<<<NB*NS, 256, 0, stream>>>(x, g, ln2s + (size_t)l*ND, ln2b + (size_t)l*ND, xb);
  }
  // final vocab projection (f32 out + bias)
  gemm_bt<128, 0, 0, true><<<dim3(NV/128, NB*NS/128, 1), 256, 0, stream>>>(
      xb, woutT, out, bout,
      NB*NS, NV, ND, ND, ND, NV, 1, 0,0, 0,0, 0,0, 0);
}